// Round 2
// baseline (223.157 us; speedup 1.0000x reference)
//
#include <hip/hip_runtime.h>
#include <stdint.h>
#include <stddef.h>

typedef __bf16 bf16;
typedef bf16 bf16x4 __attribute__((ext_vector_type(4)));
typedef bf16 bf16x8 __attribute__((ext_vector_type(8)));
typedef float f32x4 __attribute__((ext_vector_type(4)));
typedef float f32x16 __attribute__((ext_vector_type(16)));

#define T_DIM 365
#define K1    368
#define SX    376      // LDS stride (bf16) for Xb
#define SH1   520
#define SH2   264
#define SCB   184      // combined: 128 seq + 32 stat
#define SC1   72
#define SC2   33

#define ROWS  64       // rows per block (2 row-tiles of 32)

// ws element offsets (bf16 elements) — fragment-major packed layouts (UNCHANGED).
// Layer1: tile tt in [0,16), stride 11776 = 23*512;  n=32*tt+(l&31), k=16ks+(l>>5)*8+j
#define WT1_OFF  0
// Layer2: tile tt in [0,8), stride 16384 = 32*512;   n=32*tt+(l&31), k=16ks+(l>>5)*8+j
#define WT2_OFF  188416
// Layer3: tile tt in [0,4), stride 8192 = 16*512;    n=32*tt+(l&31), k=16ks+(l>>5)*8+j
#define WT3_OFF  319488
// c1: tile ct in [0,4), stride 2560 = 5*512;         n=16*ct+(l&15), k=32ks+(l>>4)*8+j
#define WTC1_OFF 352256
// c2: tile nt in [0,2), stride 1024 = 2*512;         n=16*nt+(l&15), k=32ks+(l>>4)*8+j
#define WTC2_OFF 362496
#define WTOTAL   364544

// sConst float offsets
#define OB1   0      // 512
#define OB2   512    // 256
#define OB3   768    // 128
#define OBC1  896    // 64
#define OBC2  960    // 32
#define OWS   992    // 192 (Ws row-major [6][32])
#define OBS   1184   // 32
#define OWC3  1216   // 32
#define OBC3  1248   // 1
#define NCONST 1252

__global__ void prep_weights(const float* __restrict__ W1, const float* __restrict__ W2,
                             const float* __restrict__ W3, const float* __restrict__ Wc1,
                             const float* __restrict__ Wc2, bf16* __restrict__ ws) {
    int idx = blockIdx.x * 256 + threadIdx.x;
    if (idx >= WTOTAL) return;
    if (idx < WT2_OFF) {
        int t = idx;
        int j = t & 7, lane = (t >> 3) & 63, f = t >> 9;
        int ks = f % 23; f /= 23;
        int nt = f & 3, wv = f >> 2;
        int n = 128 * wv + 32 * nt + (lane & 31);
        int k = 16 * ks + (lane >> 5) * 8 + j;
        ws[idx] = (k < T_DIM) ? (bf16)W1[k * 512 + n] : (bf16)0.0f;
    } else if (idx < WT3_OFF) {
        int t = idx - WT2_OFF;
        int j = t & 7, lane = (t >> 3) & 63, f = t >> 9;
        int ks = f & 31; f >>= 5;
        int nt = f & 1, wv = f >> 1;
        int n = 64 * wv + 32 * nt + (lane & 31);
        int k = 16 * ks + (lane >> 5) * 8 + j;
        ws[idx] = (bf16)W2[k * 256 + n];
    } else if (idx < WTC1_OFF) {
        int t = idx - WT3_OFF;
        int j = t & 7, lane = (t >> 3) & 63, f = t >> 9;
        int ks = f & 15, wv = f >> 4;
        int n = 32 * wv + (lane & 31);
        int k = 16 * ks + (lane >> 5) * 8 + j;
        ws[idx] = (bf16)W3[k * 128 + n];
    } else if (idx < WTC2_OFF) {
        int t = idx - WTC1_OFF;
        int j = t & 7, lane = (t >> 3) & 63, f = t >> 9;
        int ks = f % 5; f /= 5;
        int nt = f & 1, g = f >> 1;
        int n = 16 * (2 * g + nt) + (lane & 15);
        int k = 32 * ks + (lane >> 4) * 8 + j;
        ws[idx] = (bf16)Wc1[k * 64 + n];
    } else {
        int t = idx - WTC2_OFF;
        int j = t & 7, lane = (t >> 3) & 63, f = t >> 9;
        int ks = f & 1, nt = f >> 1;
        int n = 16 * nt + (lane & 15);
        int k = 32 * ks + (lane >> 4) * 8 + j;
        ws[idx] = (bf16)Wc2[k * 32 + n];
    }
}

__device__ inline f32x16 z16() {
    f32x16 v;
#pragma unroll
    for (int i = 0; i < 16; ++i) v[i] = 0.0f;
    return v;
}
__device__ inline f32x4 z4() {
    f32x4 v;
#pragma unroll
    for (int i = 0; i < 4; ++i) v[i] = 0.0f;
    return v;
}

// 64 rows/block, 512 threads (8 waves), 1 block/CU (LDS ~150 KB).
// Each wave does 2x the MFMA per phase vs the 32-row version; all 8 waves
// active in every phase; all bias/const loads staged to LDS in Phase A.
__global__ __launch_bounds__(512, 2) void fused_mlp(
    const float* __restrict__ x, const bf16* __restrict__ wt,
    const float* __restrict__ b1, const float* __restrict__ b2, const float* __restrict__ b3,
    const float* __restrict__ Ws, const float* __restrict__ bs,
    const float* __restrict__ bc1, const float* __restrict__ bc2,
    const float* __restrict__ Wc3, const float* __restrict__ bc3,
    float* __restrict__ out)
{
    __shared__ __align__(16) bf16 sXb[ROWS * SX];    // layer1 A; reused as H2 [64][SH2]
    __shared__ __align__(16) bf16 sH1[ROWS * SH1];   // layer2 A; reused as C1 [64][SC1]
    __shared__ __align__(16) bf16 sCB[ROWS * SCB];   // combined [seq(128) | stat(32)]
    __shared__ __align__(16) float sStat[ROWS * 8];
    __shared__ __align__(16) float sC2[ROWS * SC2];
    __shared__ __align__(16) float sConst[NCONST];

    const int tid  = threadIdx.x;
    const int lane = tid & 63;
    const int wv   = tid >> 6;        // 0..7
    const int row0 = blockIdx.x * ROWS;

    // ---------- const staging (latency hides under x loads) ----------
    sConst[OB1 + tid] = b1[tid];
    {
        int t = tid;
        if (t < 256)      sConst[OB2 + t]        = b2[t];
        else if (t < 384) sConst[OB3 + t - 256]  = b3[t - 256];
        else if (t < 448) sConst[OBC1 + t - 384] = bc1[t - 384];
        else if (t < 480) sConst[OBC2 + t - 448] = bc2[t - 448];
        else              sConst[OWS + t - 480]  = Ws[t - 480];       // Ws[0..31]
    }
    {
        int t = tid;
        if (t < 160)      sConst[OWS + 32 + t]   = Ws[32 + t];        // Ws[32..191]
        else if (t < 192) sConst[OBS + t - 160]  = bs[t - 160];
        else if (t < 224) sConst[OWC3 + t - 192] = Wc3[t - 192];
        else if (t == 224) sConst[OBC3]          = bc3[0];
    }

    // ---------- Phase A: load x tile (64 rows), stats (fp32), Xb (bf16) ----------
    {
        const int r = tid >> 3;       // row 0..63
        const int j = tid & 7;        // 8 threads per row
        const float* xr = x + (size_t)(row0 + r) * T_DIM;
        bf16* xb = sXb + r * SX;
        float s1 = 0.f, s2 = 0.f, s3 = 0.f, s4 = 0.f;
        float mn = 3.4e38f, mx = -3.4e38f;
#pragma unroll
        for (int i = 0; i < 12; ++i) {
            int c = j + 8 * i;        // float4 chunk index, 0..95
            if (c < 91) {
                float v0 = xr[4*c+0], v1 = xr[4*c+1], v2 = xr[4*c+2], v3 = xr[4*c+3];
                s1 += v0 + v1 + v2 + v3;
                float q0 = v0*v0, q1 = v1*v1, q2 = v2*v2, q3 = v3*v3;
                s2 += q0 + q1 + q2 + q3;
                s3 += q0*v0 + q1*v1 + q2*v2 + q3*v3;
                s4 += q0*q0 + q1*q1 + q2*q2 + q3*q3;
                mn = fminf(mn, fminf(fminf(v0, v1), fminf(v2, v3)));
                mx = fmaxf(mx, fmaxf(fmaxf(v0, v1), fmaxf(v2, v3)));
                bf16x4 p = { (bf16)v0, (bf16)v1, (bf16)v2, (bf16)v3 };
                *(bf16x4*)(xb + 4 * c) = p;
            } else if (c == 91) {
                float v0 = xr[364];
                float q0 = v0 * v0;
                s1 += v0; s2 += q0; s3 += q0 * v0; s4 += q0 * q0;
                mn = fminf(mn, v0); mx = fmaxf(mx, v0);
                bf16x4 p = { (bf16)v0, (bf16)0.0f, (bf16)0.0f, (bf16)0.0f };
                *(bf16x4*)(xb + 364) = p;
            }
        }
#pragma unroll
        for (int m = 1; m < 8; m <<= 1) {
            s1 += __shfl_xor(s1, m); s2 += __shfl_xor(s2, m);
            s3 += __shfl_xor(s3, m); s4 += __shfl_xor(s4, m);
            mn = fminf(mn, __shfl_xor(mn, m));
            mx = fmaxf(mx, __shfl_xor(mx, m));
        }
        if (j == 0) {
            const float Tf = (float)T_DIM;
            float mu = s1 / Tf;
            float M2 = fmaxf(s2 - s1 * mu, 0.0f);
            float M3 = s3 - 3.f * mu * s2 + 2.f * Tf * mu * mu * mu;
            float M4 = s4 - 4.f * mu * s3 + 6.f * mu * mu * s2 - 3.f * Tf * mu * mu * mu * mu;
            float var = M2 / (Tf - 1.f);
            float sd  = sqrtf(var);
            float sk  = (M3 / Tf) / (sd * sd * sd + 1e-8f);
            float ku  = (M4 / Tf) / (var * var + 1e-8f);
            float* st = sStat + r * 8;
            st[0] = mu; st[1] = sd; st[2] = mn; st[3] = mx; st[4] = sk; st[5] = ku;
        }
    }
    __syncthreads();

    // stat features: [64 rows] x (6 -> 32) into sCB cols 128..159 (from LDS consts)
    {
        const int r = tid >> 3;
        const int q = tid & 7;
        const float* st = sStat + r * 8;
        float a0 = st[0], a1 = st[1], a2 = st[2], a3 = st[3], a4 = st[4], a5 = st[5];
#pragma unroll
        for (int cc = 0; cc < 4; ++cc) {
            int n = 4 * q + cc;
            float v = sConst[OBS + n]
                    + a0 * sConst[OWS + 0*32+n] + a1 * sConst[OWS + 1*32+n]
                    + a2 * sConst[OWS + 2*32+n] + a3 * sConst[OWS + 3*32+n]
                    + a4 * sConst[OWS + 4*32+n] + a5 * sConst[OWS + 5*32+n];
            sCB[r * SCB + 128 + n] = (bf16)v;
        }
    }

    const int l31   = lane & 31;
    const int lhalf = lane >> 5;

    // ---------- Layer 1: [64,368] x [368,512] -> H1 ----------
    // wave wv: col tiles {2wv, 2wv+1}, row tiles {0,1} -> 4 MFMA/iter, 4 acc chains
    {
        f32x16 a00 = z16(), a01 = z16(), a10 = z16(), a11 = z16();
        const bf16* ap0 = sXb + l31 * SX + lhalf * 8;
        const bf16* ap1 = sXb + (32 + l31) * SX + lhalf * 8;
        const bf16* bp  = wt + WT1_OFF + (size_t)(2 * wv) * 11776 + (size_t)lane * 8;
        bf16x8 pf[2][2];
#pragma unroll
        for (int d = 0; d < 2; ++d) {
            pf[d][0] = *(const bf16x8*)(bp + d * 512);
            pf[d][1] = *(const bf16x8*)(bp + 11776 + d * 512);
        }
#pragma unroll
        for (int ks = 0; ks < 23; ++ks) {
            bf16x8 fa0 = *(const bf16x8*)(ap0 + 16 * ks);
            bf16x8 fa1 = *(const bf16x8*)(ap1 + 16 * ks);
            bf16x8 w0 = pf[ks & 1][0];
            bf16x8 w1 = pf[ks & 1][1];
            if (ks + 2 < 23) {
                pf[ks & 1][0] = *(const bf16x8*)(bp + (ks + 2) * 512);
                pf[ks & 1][1] = *(const bf16x8*)(bp + 11776 + (ks + 2) * 512);
            }
            a00 = __builtin_amdgcn_mfma_f32_32x32x16_bf16(fa0, w0, a00, 0, 0, 0);
            a01 = __builtin_amdgcn_mfma_f32_32x32x16_bf16(fa0, w1, a01, 0, 0, 0);
            a10 = __builtin_amdgcn_mfma_f32_32x32x16_bf16(fa1, w0, a10, 0, 0, 0);
            a11 = __builtin_amdgcn_mfma_f32_32x32x16_bf16(fa1, w1, a11, 0, 0, 0);
        }
#pragma unroll
        for (int nt = 0; nt < 2; ++nt) {
            int col = 64 * wv + 32 * nt + l31;
            float bias = sConst[OB1 + col];
            const f32x16& am0 = nt ? a01 : a00;
            const f32x16& am1 = nt ? a11 : a10;
#pragma unroll
            for (int g = 0; g < 4; ++g) {
#pragma unroll
                for (int rr = 0; rr < 4; ++rr) {
                    int rowi = rr + 8 * g + 4 * lhalf;
                    sH1[rowi * SH1 + col]        = (bf16)fmaxf(am0[4 * g + rr] + bias, 0.0f);
                    sH1[(32 + rowi) * SH1 + col] = (bf16)fmaxf(am1[4 * g + rr] + bias, 0.0f);
                }
            }
        }
    }
    __syncthreads();

    // ---------- Layer 2: [64,512] x [512,256] -> H2 (in sXb region) ----------
    // wave wv: col tile wv, row tiles {0,1} -> 2 MFMA/iter
    {
        f32x16 ac0 = z16(), ac1 = z16();
        const bf16* ap0 = sH1 + l31 * SH1 + lhalf * 8;
        const bf16* ap1 = sH1 + (32 + l31) * SH1 + lhalf * 8;
        const bf16* bp  = wt + WT2_OFF + (size_t)wv * 16384 + (size_t)lane * 8;
        bf16x8 pf[4];
#pragma unroll
        for (int d = 0; d < 4; ++d)
            pf[d] = *(const bf16x8*)(bp + d * 512);
#pragma unroll
        for (int ks = 0; ks < 32; ++ks) {
            bf16x8 fa0 = *(const bf16x8*)(ap0 + 16 * ks);
            bf16x8 fa1 = *(const bf16x8*)(ap1 + 16 * ks);
            bf16x8 w = pf[ks & 3];
            if (ks + 4 < 32)
                pf[ks & 3] = *(const bf16x8*)(bp + (ks + 4) * 512);
            ac0 = __builtin_amdgcn_mfma_f32_32x32x16_bf16(fa0, w, ac0, 0, 0, 0);
            ac1 = __builtin_amdgcn_mfma_f32_32x32x16_bf16(fa1, w, ac1, 0, 0, 0);
        }
        bf16* H2 = sXb;
        int col = 32 * wv + l31;
        float bias = sConst[OB2 + col];
#pragma unroll
        for (int g = 0; g < 4; ++g) {
#pragma unroll
            for (int rr = 0; rr < 4; ++rr) {
                int rowi = rr + 8 * g + 4 * lhalf;
                H2[rowi * SH2 + col]        = (bf16)fmaxf(ac0[4 * g + rr] + bias, 0.0f);
                H2[(32 + rowi) * SH2 + col] = (bf16)fmaxf(ac1[4 * g + rr] + bias, 0.0f);
            }
        }
    }
    __syncthreads();

    // ---------- Layer 3: [64,256] x [256,128] -> seq (sCB cols 0..127) ----------
    // wave wv: col tile wv&3, row tile wv>>2 -> all 8 waves active
    {
        const int ct = wv & 3;
        const int m3 = wv >> 2;
        f32x16 acc = z16();
        const bf16* H2 = sXb;
        const bf16* ap = H2 + (32 * m3 + l31) * SH2 + lhalf * 8;
        const bf16* bp = wt + WT3_OFF + (size_t)ct * 8192 + (size_t)lane * 8;
        bf16x8 pf[4];
#pragma unroll
        for (int d = 0; d < 4; ++d)
            pf[d] = *(const bf16x8*)(bp + d * 512);
#pragma unroll
        for (int ks = 0; ks < 16; ++ks) {
            bf16x8 a = *(const bf16x8*)(ap + 16 * ks);
            bf16x8 w = pf[ks & 3];
            if (ks + 4 < 16)
                pf[ks & 3] = *(const bf16x8*)(bp + (ks + 4) * 512);
            acc = __builtin_amdgcn_mfma_f32_32x32x16_bf16(a, w, acc, 0, 0, 0);
        }
        int col = 32 * ct + l31;
        float bias = sConst[OB3 + col];
#pragma unroll
        for (int g = 0; g < 4; ++g) {
#pragma unroll
            for (int rr = 0; rr < 4; ++rr) {
                int rowi = 32 * m3 + rr + 8 * g + 4 * lhalf;
                sCB[rowi * SCB + col] = (bf16)fmaxf(acc[4 * g + rr] + bias, 0.0f);
            }
        }
    }
    __syncthreads();

    // ---------- Layer c1: [64,160] x [160,64] -> C1 (16x16x32 MFMA) ----------
    // wave wv: row tile mt = wv&3 (of 4), col tiles {2g2, 2g2+1}, g2 = wv>>2
    {
        const int l15 = lane & 15;
        const int lq  = lane >> 4;
        const int mt  = wv & 3;
        const int g2  = wv >> 2;
        f32x4 ac0 = z4(), ac1 = z4();
        const bf16* ap = sCB + (16 * mt + l15) * SCB + lq * 8;
        const bf16* bp = wt + WTC1_OFF + (size_t)g2 * 5120 + (size_t)lane * 8;
        bf16x8 av[5], w0[5], w1[5];
#pragma unroll
        for (int ks = 0; ks < 5; ++ks) {
            w0[ks] = *(const bf16x8*)(bp + ks * 512);
            w1[ks] = *(const bf16x8*)(bp + 2560 + ks * 512);
            av[ks] = *(const bf16x8*)(ap + 32 * ks);
        }
#pragma unroll
        for (int ks = 0; ks < 5; ++ks) {
            ac0 = __builtin_amdgcn_mfma_f32_16x16x32_bf16(av[ks], w0[ks], ac0, 0, 0, 0);
            ac1 = __builtin_amdgcn_mfma_f32_16x16x32_bf16(av[ks], w1[ks], ac1, 0, 0, 0);
        }
        bf16* C1 = sH1;
#pragma unroll
        for (int nt = 0; nt < 2; ++nt) {
            int col = 16 * (2 * g2 + nt) + l15;
            float bias = sConst[OBC1 + col];
            const f32x4& ac = nt ? ac1 : ac0;
#pragma unroll
            for (int reg = 0; reg < 4; ++reg) {
                int m = 16 * mt + lq * 4 + reg;
                C1[m * SC1 + col] = (bf16)fmaxf(ac[reg] + bias, 0.0f);
            }
        }
    }
    __syncthreads();

    // ---------- Layer c2: [64,64] x [64,32] -> C2 (f32 in LDS) ----------
    // wave wv: row tile mt = wv&3, col tile nt2 = wv>>2
    {
        const int l15 = lane & 15;
        const int lq  = lane >> 4;
        const int mt  = wv & 3;
        const int nt2 = wv >> 2;
        f32x4 acc = z4();
        const bf16* C1 = sH1;
        const bf16* ap = C1 + (16 * mt + l15) * SC1 + lq * 8;
        const bf16* bp = wt + WTC2_OFF + (size_t)nt2 * 1024 + (size_t)lane * 8;
        bf16x8 av[2], wvv[2];
#pragma unroll
        for (int ks = 0; ks < 2; ++ks) {
            wvv[ks] = *(const bf16x8*)(bp + ks * 512);
            av[ks]  = *(const bf16x8*)(ap + 32 * ks);
        }
#pragma unroll
        for (int ks = 0; ks < 2; ++ks)
            acc = __builtin_amdgcn_mfma_f32_16x16x32_bf16(av[ks], wvv[ks], acc, 0, 0, 0);
        int col = 16 * nt2 + l15;
        float bias = sConst[OBC2 + col];
#pragma unroll
        for (int reg = 0; reg < 4; ++reg) {
            int m = 16 * mt + lq * 4 + reg;
            sC2[m * SC2 + col] = fmaxf(acc[reg] + bias, 0.0f);
        }
    }
    __syncthreads();

    // ---------- final: 32 -> 1 dot, sigmoid*4+6 ----------
    if (tid < ROWS) {
        const float* c2r = sC2 + tid * SC2;
        float z = sConst[OBC3];
#pragma unroll
        for (int k = 0; k < 32; ++k) z += c2r[k] * sConst[OWC3 + k];
        float sg = 1.0f / (1.0f + __expf(-z));
        out[row0 + tid] = sg * 4.0f + 6.0f;
    }
}

extern "C" void kernel_launch(void* const* d_in, const int* in_sizes, int n_in,
                              void* d_out, int out_size, void* d_ws, size_t ws_size,
                              hipStream_t stream) {
    const float* x   = (const float*)d_in[0];
    const float* W1  = (const float*)d_in[1];
    const float* b1  = (const float*)d_in[2];
    const float* W2  = (const float*)d_in[3];
    const float* b2  = (const float*)d_in[4];
    const float* W3  = (const float*)d_in[5];
    const float* b3  = (const float*)d_in[6];
    const float* Ws  = (const float*)d_in[7];
    const float* bs  = (const float*)d_in[8];
    const float* Wc1 = (const float*)d_in[9];
    const float* bc1 = (const float*)d_in[10];
    const float* Wc2 = (const float*)d_in[11];
    const float* bc2 = (const float*)d_in[12];
    const float* Wc3 = (const float*)d_in[13];
    const float* bc3 = (const float*)d_in[14];
    float* out = (float*)d_out;
    bf16* wt = (bf16*)d_ws;

    const int B = in_sizes[0] / T_DIM;          // 65536
    prep_weights<<<(WTOTAL + 255) / 256, 256, 0, stream>>>(W1, W2, W3, Wc1, Wc2, wt);
    fused_mlp<<<B / ROWS, 512, 0, stream>>>(x, wt, b1, b2, b3, Ws, bs, bc1, bc2, Wc3, bc3, out);
}